// Round 9
// baseline (243.374 us; speedup 1.0000x reference)
//
#include <hip/hip_runtime.h>
#include <math.h>

#define H 128
#define NF 100000
#define NC 25000

typedef _Float16 f16;
typedef f16 f16x8 __attribute__((ext_vector_type(8)));
typedef float f32x4 __attribute__((ext_vector_type(4)));

#define MFMA16(a, b, c) __builtin_amdgcn_mfma_f32_16x16x32_f16((a), (b), (c), 0, 0, 0)

// ws layout in f16 elements:
//   0      WT1 [128][256]  (W1^T over k<256; W1 row 256 folded as rank-1 f32 into init)
//   32768  WT2 [128][128]
//   49152  WT3 [128][128]

__global__ void prep_w(const float* __restrict__ W1, const float* __restrict__ W2,
                       const float* __restrict__ W3, f16* __restrict__ ws)
{
    int i = blockIdx.x * 256 + threadIdx.x;   // 0..65535, grid exact
    if (i < 32768) {                          // W1^T: n = i>>8, k = i&255
        int n = i >> 8, k = i & 255;
        ws[i] = (f16)W1[k * H + n];
    } else if (i < 49152) {                   // W2^T
        int j = i - 32768, n = j >> 7, k = j & 127;
        ws[32768 + j] = (f16)W2[k * H + n];
    } else {                                  // W3^T
        int j = i - 49152, n = j >> 7, k = j & 127;
        ws[49152 + j] = (f16)W3[k * H + n];
    }
}

__device__ __forceinline__ float silu_f(float v) {
    return v / (1.0f + __expf(-v));
}

// element index into a [16][H] f16 plane with 16B-slot XOR swizzle
__device__ __forceinline__ int swz(int row, int col) {
    return row * H + (((col >> 3) ^ (row & 7)) << 3) + (col & 7);
}

// A-fragment read from a wave's LDS h-slice: row (0..15), k (mult of 8)
__device__ __forceinline__ f16x8 ldsA(const f16* __restrict__ p, int row, int k) {
    int idx = row * H + ((((k >> 3) ^ (row & 7))) << 3);
    return *(const f16x8*)(p + idx);
}

// convert 8 f32 to f16 fragment
__device__ __forceinline__ f16x8 cvt8(float4 v0, float4 v1) {
    f16x8 r;
    r[0] = (f16)v0.x; r[1] = (f16)v0.y; r[2] = (f16)v0.z; r[3] = (f16)v0.w;
    r[4] = (f16)v1.x; r[5] = (f16)v1.y; r[6] = (f16)v1.z; r[7] = (f16)v1.w;
    return r;
}

// Fully wave-independent kernel: each wave owns 16 rows x 128 cols, its own
// 4 KB LDS h-slice, and NO __syncthreads anywhere (LDS ops are wave-ordered).
__global__ __launch_bounds__(256, 4)
void fused_mlp_wave(const float* __restrict__ x,     // [2][25000][128]
                    const float* __restrict__ xsc,   // [2][100000][128]
                    const int*   __restrict__ f2c,   // [100000]
                    const float* __restrict__ dist,  // [100000]
                    const float* __restrict__ W1,    // [257][128] (row 256 used)
                    const float* __restrict__ b1,
                    const float* __restrict__ b2,
                    const float* __restrict__ b3,
                    const f16*   __restrict__ ws,
                    float* __restrict__ out)         // [200000][128]
{
    __shared__ __align__(16) f16 sH[4 * 16 * H];     // 16 KB, 4 KB per wave

    const int t   = threadIdx.x;
    const int wid = t >> 6, l = t & 63;
    const int lr  = l & 15, lg = l >> 4;

    const int R0w = blockIdx.x * 64 + wid * 16;      // wave's base row (< 200000)
    const int bb  = R0w >= NF;                       // NF % 16 == 0: no straddle
    const int nnw = R0w - bb * NF;

    const int ci = f2c[nnw + lr];
    const float* xg = x   + ((long long)bb * NC + ci) * H;   // this lane's gathered row
    const float* xs = xsc + ((long long)R0w + lr) * H;       // this lane's fine row

    float4 d4v = *(const float4*)(dist + nnw + lg * 4);      // d for rows lg*4..lg*4+3
    float dd[4] = {d4v.x, d4v.y, d4v.z, d4v.w};

    f16* sHw = sH + wid * (16 * H);

    const f16* WT1 = ws;
    const f16* WT2 = ws + 32768;
    const f16* WT3 = ws + 49152;

    // ---- layer 1: acc = b1 + d*W1[256] + concat(xg,xs) @ W1[0:256] ----
    f32x4 acc[8];
    #pragma unroll
    for (int nt = 0; nt < 8; ++nt) {
        int col = nt * 16 + lr;
        float bc = b1[col];
        float wc = W1[256 * H + col];
        #pragma unroll
        for (int r = 0; r < 4; ++r)
            acc[nt][r] = bc + dd[r] * wc;
    }

    // xg part: W1^T k in [0,128)
    #pragma unroll
    for (int kk = 0; kk < 4; ++kk) {
        const int kc = kk * 32 + (lg << 3);
        f16x8 a = cvt8(*(const float4*)(xg + kc), *(const float4*)(xg + kc + 4));
        #pragma unroll
        for (int nt = 0; nt < 8; ++nt) {
            f16x8 wv = *(const f16x8*)(WT1 + (nt * 16 + lr) * 256 + kc);
            acc[nt] = MFMA16(a, wv, acc[nt]);
        }
    }
    // xs part: W1^T k in [128,256)
    #pragma unroll
    for (int kk = 0; kk < 4; ++kk) {
        const int kc = kk * 32 + (lg << 3);
        f16x8 a = cvt8(*(const float4*)(xs + kc), *(const float4*)(xs + kc + 4));
        #pragma unroll
        for (int nt = 0; nt < 8; ++nt) {
            f16x8 wv = *(const f16x8*)(WT1 + (nt * 16 + lr) * 256 + 128 + kc);
            acc[nt] = MFMA16(a, wv, acc[nt]);
        }
    }

    // h1 -> own LDS slice (rows 0..15 local)
    #pragma unroll
    for (int nt = 0; nt < 8; ++nt)
        #pragma unroll
        for (int r = 0; r < 4; ++r)
            sHw[swz(lg * 4 + r, nt * 16 + lr)] = (f16)silu_f(acc[nt][r]);

    // ---- layer 2 ----
    #pragma unroll
    for (int nt = 0; nt < 8; ++nt) {
        float bc = b2[nt * 16 + lr];
        #pragma unroll
        for (int r = 0; r < 4; ++r)
            acc[nt][r] = bc;
    }
    #pragma unroll
    for (int kk = 0; kk < 4; ++kk) {
        const int k = kk * 32 + (lg << 3);
        f16x8 a = ldsA(sHw, lr, k);
        #pragma unroll
        for (int nt = 0; nt < 8; ++nt) {
            f16x8 wv = *(const f16x8*)(WT2 + (nt * 16 + lr) * 128 + k);
            acc[nt] = MFMA16(a, wv, acc[nt]);
        }
    }

    // h2 -> own LDS slice (overwrites h1; wave-ordered LDS, no barrier needed)
    #pragma unroll
    for (int nt = 0; nt < 8; ++nt)
        #pragma unroll
        for (int r = 0; r < 4; ++r)
            sHw[swz(lg * 4 + r, nt * 16 + lr)] = (f16)silu_f(acc[nt][r]);

    // ---- layer 3 ----
    #pragma unroll
    for (int nt = 0; nt < 8; ++nt) {
        float bc = b3[nt * 16 + lr];
        #pragma unroll
        for (int r = 0; r < 4; ++r)
            acc[nt][r] = bc;
    }
    #pragma unroll
    for (int kk = 0; kk < 4; ++kk) {
        const int k = kk * 32 + (lg << 3);
        f16x8 a = ldsA(sHw, lr, k);
        #pragma unroll
        for (int nt = 0; nt < 8; ++nt) {
            f16x8 wv = *(const f16x8*)(WT3 + (nt * 16 + lr) * 128 + k);
            acc[nt] = MFMA16(a, wv, acc[nt]);
        }
    }

    // ---- store out ----
    #pragma unroll
    for (int nt = 0; nt < 8; ++nt)
        #pragma unroll
        for (int r = 0; r < 4; ++r)
            out[(long long)(R0w + lg * 4 + r) * H + nt * 16 + lr] = acc[nt][r];
}

extern "C" void kernel_launch(void* const* d_in, const int* in_sizes, int n_in,
                              void* d_out, int out_size, void* d_ws, size_t ws_size,
                              hipStream_t stream)
{
    const float* x    = (const float*)d_in[0];
    const float* xsc  = (const float*)d_in[1];
    const int*   f2c  = (const int*)d_in[2];
    const float* dist = (const float*)d_in[3];
    const float* W1   = (const float*)d_in[4];
    const float* b1   = (const float*)d_in[5];
    const float* W2   = (const float*)d_in[6];
    const float* b2   = (const float*)d_in[7];
    const float* W3   = (const float*)d_in[8];
    const float* b3   = (const float*)d_in[9];
    f16* ws = (f16*)d_ws;

    prep_w<<<256, 256, 0, stream>>>(W1, W2, W3, ws);

    const int n_rows = 2 * NF;                    // 200000
    dim3 grid(n_rows / 64);                       // 3125 blocks x 4 independent waves
    fused_mlp_wave<<<grid, 256, 0, stream>>>(x, xsc, f2c, dist, W1, b1, b2, b3,
                                             ws, (float*)d_out);
}

// Round 10
// 79.447 us; speedup vs baseline: 3.0634x; 3.0634x over previous
//
#include <hip/hip_runtime.h>
#include <math.h>

#define H 128
#define NF 100000
#define NC 25000
#define TM 64

typedef _Float16 f16;
typedef f16 f16x8 __attribute__((ext_vector_type(8)));
typedef f16 f16x4 __attribute__((ext_vector_type(4)));
typedef float f32x4 __attribute__((ext_vector_type(4)));

#define MFMA16(a, b, c) __builtin_amdgcn_mfma_f32_16x16x32_f16((a), (b), (c), 0, 0, 0)

// ws: fragment-ordered f16 weights (each fragment = 64 lanes x 8 f16 = 1 KB contiguous)
//   F1 @ 0     : [nt=8][kk=8][lane=64][8]   W1^T, k<256   (32768 f16)
//   F2 @ 32768 : [nt=8][kk=4][lane=64][8]   W2^T          (16384 f16)
//   F3 @ 49152 : [nt=8][kk=4][lane=64][8]   W3^T          (16384 f16)
// fragment element: n = nt*16 + (lane&15), k = kk*32 + (lane>>4)*8 + j

__global__ void prep_w(const float* __restrict__ W1, const float* __restrict__ W2,
                       const float* __restrict__ W3, f16* __restrict__ ws)
{
    int i = blockIdx.x * 256 + threadIdx.x;   // 0..65535, grid exact
    if (i < 32768) {
        int j = i & 7, lane = (i >> 3) & 63, kk = (i >> 9) & 7, nt = i >> 12;
        int n = nt * 16 + (lane & 15);
        int k = kk * 32 + (lane >> 4) * 8 + j;
        ws[i] = (f16)W1[k * H + n];
    } else if (i < 49152) {
        int q = i - 32768;
        int j = q & 7, lane = (q >> 3) & 63, kk = (q >> 9) & 3, nt = q >> 11;
        int n = nt * 16 + (lane & 15);
        int k = kk * 32 + (lane >> 4) * 8 + j;
        ws[i] = (f16)W2[k * H + n];
    } else {
        int q = i - 49152;
        int j = q & 7, lane = (q >> 3) & 63, kk = (q >> 9) & 3, nt = q >> 11;
        int n = nt * 16 + (lane & 15);
        int k = kk * 32 + (lane >> 4) * 8 + j;
        ws[i] = (f16)W3[k * H + n];
    }
}

__device__ __forceinline__ float silu_f(float v) {
    return v / (1.0f + __expf(-v));
}

__global__ __launch_bounds__(256, 4)
void fused_mlp_v10(const float* __restrict__ x,     // [2][25000][128]
                   const float* __restrict__ xsc,   // [2][100000][128]
                   const int*   __restrict__ f2c,   // [100000]
                   const float* __restrict__ dist,  // [100000]
                   const float* __restrict__ W1,    // [257][128] (row 256 used as f32)
                   const float* __restrict__ b1,
                   const float* __restrict__ b2,
                   const float* __restrict__ b3,
                   const f16*   __restrict__ ws,
                   float* __restrict__ out)         // [200000][128]
{
    // sA: layer-1 A tile [64][256] f16 swizzled (xg cols 0..127, xs cols 128..255);
    // reused after layer 1 as h-plane [64][128] f16 swizzled.
    __shared__ __align__(16) f16 sA[TM * 256];       // 32 KB
    __shared__ float sD[TM];
    __shared__ int   sCI[TM];                        // absolute coarse row index

    const int t = threadIdx.x;
    const int l = t & 63, w = t >> 6;
    const int wRow = (w >> 1) * 32;                  // 0 or 32
    const int wnt  = (w & 1) * 4;                    // first n-tile (of 8) for this wave
    const int lr = l & 15, lg = l >> 4;
    const int R0 = blockIdx.x * TM;

    // ---- per-row metadata ----
    if (t < TM) {
        int Rs = R0 + t;
        int bb = Rs >= NF;
        int nn = Rs - bb * NF;
        sCI[t] = bb * NC + f2c[nn];
        sD[t]  = dist[nn];
    }
    __syncthreads();                                 // B0: meta ready

    // ---- stage A: coalesced f32 loads -> f16 swizzled LDS ----
    // xs -> cols [128,256)
    #pragma unroll
    for (int i = 0; i < 8; ++i) {
        int f = i * 256 + t;
        int row = f >> 5, col = (f & 31) * 4;
        float4 v = *(const float4*)(xsc + (long long)(R0 + row) * H + col);
        f16x4 hv; hv[0] = (f16)v.x; hv[1] = (f16)v.y; hv[2] = (f16)v.z; hv[3] = (f16)v.w;
        int c = 128 + col;
        *(f16x4*)(sA + row * 256 + (((c >> 3) ^ (row & 7)) << 3) + (c & 7)) = hv;
    }
    // xg (gathered coarse rows) -> cols [0,128)
    #pragma unroll
    for (int i = 0; i < 8; ++i) {
        int f = i * 256 + t;
        int row = f >> 5, col = (f & 31) * 4;
        float4 v = *(const float4*)(x + (long long)sCI[row] * H + col);
        f16x4 hv; hv[0] = (f16)v.x; hv[1] = (f16)v.y; hv[2] = (f16)v.z; hv[3] = (f16)v.w;
        *(f16x4*)(sA + row * 256 + (((col >> 3) ^ (row & 7)) << 3) + (col & 7)) = hv;
    }
    __syncthreads();                                 // B1: A tile ready

    const f16* F1 = ws;
    const f16* F2 = ws + 32768;
    const f16* F3 = ws + 49152;

    // ---- layer 1: acc = b1 + d*W1[256] + concat(xg,xs) @ W1[0:256] ----
    f32x4 acc[2][4];
    #pragma unroll
    for (int nt = 0; nt < 4; ++nt) {
        int col = (wnt + nt) * 16 + lr;
        float bc = b1[col];
        float wc = W1[256 * H + col];
        #pragma unroll
        for (int mt = 0; mt < 2; ++mt)
            #pragma unroll
            for (int r = 0; r < 4; ++r)
                acc[mt][nt][r] = bc + sD[wRow + mt * 16 + lg * 4 + r] * wc;
    }

    // half 0: xg  (A cols 0..127, W1 fragments kk=0..3)
    {
        f16x8 wv[4][4];
        #pragma unroll
        for (int kk = 0; kk < 4; ++kk)
            #pragma unroll
            for (int nt = 0; nt < 4; ++nt)
                wv[kk][nt] = *(const f16x8*)(F1 + ((((wnt + nt) * 8 + kk) * 64 + l) << 3));
        #pragma unroll
        for (int kk = 0; kk < 4; ++kk) {
            int k = kk * 32 + (lg << 3);
            int slot = (((k >> 3) ^ (lr & 7)) << 3);
            f16x8 a0 = *(const f16x8*)(sA + (wRow + lr) * 256 + slot);
            f16x8 a1 = *(const f16x8*)(sA + (wRow + 16 + lr) * 256 + slot);
            #pragma unroll
            for (int nt = 0; nt < 4; ++nt) {
                acc[0][nt] = MFMA16(a0, wv[kk][nt], acc[0][nt]);
                acc[1][nt] = MFMA16(a1, wv[kk][nt], acc[1][nt]);
            }
        }
    }
    // half 1: xs  (A cols 128..255, W1 fragments kk=4..7)
    {
        f16x8 wv[4][4];
        #pragma unroll
        for (int kk = 0; kk < 4; ++kk)
            #pragma unroll
            for (int nt = 0; nt < 4; ++nt)
                wv[kk][nt] = *(const f16x8*)(F1 + ((((wnt + nt) * 8 + kk + 4) * 64 + l) << 3));
        #pragma unroll
        for (int kk = 0; kk < 4; ++kk) {
            int k = 128 + kk * 32 + (lg << 3);
            int slot = (((k >> 3) ^ (lr & 7)) << 3);
            f16x8 a0 = *(const f16x8*)(sA + (wRow + lr) * 256 + slot);
            f16x8 a1 = *(const f16x8*)(sA + (wRow + 16 + lr) * 256 + slot);
            #pragma unroll
            for (int nt = 0; nt < 4; ++nt) {
                acc[0][nt] = MFMA16(a0, wv[kk][nt], acc[0][nt]);
                acc[1][nt] = MFMA16(a1, wv[kk][nt], acc[1][nt]);
            }
        }
    }

    __syncthreads();                                 // B2: sA (A tile) dead
    // h1 -> sA reused as [64][128] swizzled
    #pragma unroll
    for (int nt = 0; nt < 4; ++nt)
        #pragma unroll
        for (int mt = 0; mt < 2; ++mt)
            #pragma unroll
            for (int r = 0; r < 4; ++r) {
                int row = wRow + mt * 16 + lg * 4 + r;
                int col = (wnt + nt) * 16 + lr;
                sA[row * 128 + (((col >> 3) ^ (row & 7)) << 3) + (col & 7)] =
                    (f16)silu_f(acc[mt][nt][r]);
            }
    __syncthreads();                                 // B3: h1 ready

    // ---- layer 2 ----
    #pragma unroll
    for (int nt = 0; nt < 4; ++nt) {
        float bc = b2[(wnt + nt) * 16 + lr];
        #pragma unroll
        for (int mt = 0; mt < 2; ++mt)
            #pragma unroll
            for (int r = 0; r < 4; ++r)
                acc[mt][nt][r] = bc;
    }
    {
        f16x8 wv[4][4];
        #pragma unroll
        for (int kk = 0; kk < 4; ++kk)
            #pragma unroll
            for (int nt = 0; nt < 4; ++nt)
                wv[kk][nt] = *(const f16x8*)(F2 + ((((wnt + nt) * 4 + kk) * 64 + l) << 3));
        #pragma unroll
        for (int kk = 0; kk < 4; ++kk) {
            int k = kk * 32 + (lg << 3);
            int slot = (((k >> 3) ^ (lr & 7)) << 3);
            f16x8 a0 = *(const f16x8*)(sA + (wRow + lr) * 128 + slot);
            f16x8 a1 = *(const f16x8*)(sA + (wRow + 16 + lr) * 128 + slot);
            #pragma unroll
            for (int nt = 0; nt < 4; ++nt) {
                acc[0][nt] = MFMA16(a0, wv[kk][nt], acc[0][nt]);
                acc[1][nt] = MFMA16(a1, wv[kk][nt], acc[1][nt]);
            }
        }
    }

    __syncthreads();                                 // B4: h1 dead
    // h2 -> sA
    #pragma unroll
    for (int nt = 0; nt < 4; ++nt)
        #pragma unroll
        for (int mt = 0; mt < 2; ++mt)
            #pragma unroll
            for (int r = 0; r < 4; ++r) {
                int row = wRow + mt * 16 + lg * 4 + r;
                int col = (wnt + nt) * 16 + lr;
                sA[row * 128 + (((col >> 3) ^ (row & 7)) << 3) + (col & 7)] =
                    (f16)silu_f(acc[mt][nt][r]);
            }
    __syncthreads();                                 // B5: h2 ready

    // ---- layer 3 ----
    #pragma unroll
    for (int nt = 0; nt < 4; ++nt) {
        float bc = b3[(wnt + nt) * 16 + lr];
        #pragma unroll
        for (int mt = 0; mt < 2; ++mt)
            #pragma unroll
            for (int r = 0; r < 4; ++r)
                acc[mt][nt][r] = bc;
    }
    {
        f16x8 wv[4][4];
        #pragma unroll
        for (int kk = 0; kk < 4; ++kk)
            #pragma unroll
            for (int nt = 0; nt < 4; ++nt)
                wv[kk][nt] = *(const f16x8*)(F3 + ((((wnt + nt) * 4 + kk) * 64 + l) << 3));
        #pragma unroll
        for (int kk = 0; kk < 4; ++kk) {
            int k = kk * 32 + (lg << 3);
            int slot = (((k >> 3) ^ (lr & 7)) << 3);
            f16x8 a0 = *(const f16x8*)(sA + (wRow + lr) * 128 + slot);
            f16x8 a1 = *(const f16x8*)(sA + (wRow + 16 + lr) * 128 + slot);
            #pragma unroll
            for (int nt = 0; nt < 4; ++nt) {
                acc[0][nt] = MFMA16(a0, wv[kk][nt], acc[0][nt]);
                acc[1][nt] = MFMA16(a1, wv[kk][nt], acc[1][nt]);
            }
        }
    }

    // ---- store out (64 B row-segments, sector-aligned) ----
    #pragma unroll
    for (int mt = 0; mt < 2; ++mt)
        #pragma unroll
        for (int nt = 0; nt < 4; ++nt)
            #pragma unroll
            for (int r = 0; r < 4; ++r) {
                long long row = (long long)R0 + wRow + mt * 16 + lg * 4 + r;
                int col = (wnt + nt) * 16 + lr;
                out[row * H + col] = acc[mt][nt][r];
            }
}

extern "C" void kernel_launch(void* const* d_in, const int* in_sizes, int n_in,
                              void* d_out, int out_size, void* d_ws, size_t ws_size,
                              hipStream_t stream)
{
    const float* x    = (const float*)d_in[0];
    const float* xsc  = (const float*)d_in[1];
    const int*   f2c  = (const int*)d_in[2];
    const float* dist = (const float*)d_in[3];
    const float* W1   = (const float*)d_in[4];
    const float* b1   = (const float*)d_in[5];
    const float* W2   = (const float*)d_in[6];
    const float* b2   = (const float*)d_in[7];
    const float* W3   = (const float*)d_in[8];
    const float* b3   = (const float*)d_in[9];
    f16* ws = (f16*)d_ws;

    prep_w<<<256, 256, 0, stream>>>(W1, W2, W3, ws);

    const int n_rows = 2 * NF;                    // 200000
    dim3 grid(n_rows / TM);                       // 3125
    fused_mlp_v10<<<grid, 256, 0, stream>>>(x, xsc, f2c, dist, W1, b1, b2, b3,
                                            ws, (float*)d_out);
}

// Round 11
// 76.946 us; speedup vs baseline: 3.1629x; 1.0325x over previous
//
#include <hip/hip_runtime.h>
#include <math.h>

#define H 128
#define NF 100000
#define NC 25000
#define TM 64

typedef _Float16 f16;
typedef f16 f16x8 __attribute__((ext_vector_type(8)));
typedef f16 f16x4 __attribute__((ext_vector_type(4)));
typedef float f32x4 __attribute__((ext_vector_type(4)));

#define MFMA16(a, b, c) __builtin_amdgcn_mfma_f32_16x16x32_f16((a), (b), (c), 0, 0, 0)

// ws: fragment-ordered f16 weights (each fragment = 64 lanes x 8 f16 = 1 KB contiguous)
//   F1 @ 0     : [nt=8][kk=8][lane=64][8]   W1^T, k<256   (32768 f16)
//   F2 @ 32768 : [nt=8][kk=4][lane=64][8]   W2^T          (16384 f16)
//   F3 @ 49152 : [nt=8][kk=4][lane=64][8]   W3^T          (16384 f16)
// fragment element: n = nt*16 + (lane&15), k = kk*32 + (lane>>4)*8 + j

__global__ void prep_w(const float* __restrict__ W1, const float* __restrict__ W2,
                       const float* __restrict__ W3, f16* __restrict__ ws)
{
    int i = blockIdx.x * 256 + threadIdx.x;   // 0..65535, grid exact
    if (i < 32768) {
        int j = i & 7, lane = (i >> 3) & 63, kk = (i >> 9) & 7, nt = i >> 12;
        int n = nt * 16 + (lane & 15);
        int k = kk * 32 + (lane >> 4) * 8 + j;
        ws[i] = (f16)W1[k * H + n];
    } else if (i < 49152) {
        int q = i - 32768;
        int j = q & 7, lane = (q >> 3) & 63, kk = (q >> 9) & 3, nt = q >> 11;
        int n = nt * 16 + (lane & 15);
        int k = kk * 32 + (lane >> 4) * 8 + j;
        ws[i] = (f16)W2[k * H + n];
    } else {
        int q = i - 49152;
        int j = q & 7, lane = (q >> 3) & 63, kk = (q >> 9) & 3, nt = q >> 11;
        int n = nt * 16 + (lane & 15);
        int k = kk * 32 + (lane >> 4) * 8 + j;
        ws[i] = (f16)W3[k * H + n];
    }
}

__device__ __forceinline__ float silu_f(float v) {
    return v / (1.0f + __expf(-v));
}

// Single 16 KB activation buffer [64][128] f16, swizzled; used for xg, then xs,
// then h1, then h2 (two-phase layer-1, barrier-separated reuse).
__global__ __launch_bounds__(256, 4)
void fused_mlp_v11(const float* __restrict__ x,     // [2][25000][128]
                   const float* __restrict__ xsc,   // [2][100000][128]
                   const int*   __restrict__ f2c,   // [100000]
                   const float* __restrict__ dist,  // [100000]
                   const float* __restrict__ W1,    // [257][128] (row 256 used as f32)
                   const float* __restrict__ b1,
                   const float* __restrict__ b2,
                   const float* __restrict__ b3,
                   const f16*   __restrict__ ws,
                   float* __restrict__ out)         // [200000][128]
{
    __shared__ __align__(16) f16 sA[TM * H];         // 16 KB
    __shared__ float sD[TM];
    __shared__ int   sCI[TM];                        // absolute coarse row index

    const int t = threadIdx.x;
    const int l = t & 63, w = t >> 6;
    const int wRow = (w >> 1) * 32;                  // 0 or 32
    const int wnt  = (w & 1) * 4;                    // first n-tile (of 8) for this wave
    const int lr = l & 15, lg = l >> 4;
    const int R0 = blockIdx.x * TM;

    // ---- per-row metadata ----
    if (t < TM) {
        int Rs = R0 + t;
        int bb = Rs >= NF;
        int nn = Rs - bb * NF;
        sCI[t] = bb * NC + f2c[nn];
        sD[t]  = dist[nn];
    }
    __syncthreads();                                 // B0: meta ready

    const f16* F1 = ws;
    const f16* F2 = ws + 32768;
    const f16* F3 = ws + 49152;

    // ---- acc init: b1 + d*W1[256] ----
    f32x4 acc[2][4];
    #pragma unroll
    for (int nt = 0; nt < 4; ++nt) {
        int col = (wnt + nt) * 16 + lr;
        float bc = b1[col];
        float wc = W1[256 * H + col];
        #pragma unroll
        for (int mt = 0; mt < 2; ++mt)
            #pragma unroll
            for (int r = 0; r < 4; ++r)
                acc[mt][nt][r] = bc + sD[wRow + mt * 16 + lg * 4 + r] * wc;
    }

    // ---- phase 1: stage xg (gathered coarse rows) ----
    #pragma unroll
    for (int i = 0; i < 8; ++i) {
        int f = i * 256 + t;
        int row = f >> 5, col = (f & 31) * 4;
        float4 v = *(const float4*)(x + (long long)sCI[row] * H + col);
        f16x4 hv; hv[0] = (f16)v.x; hv[1] = (f16)v.y; hv[2] = (f16)v.z; hv[3] = (f16)v.w;
        *(f16x4*)(sA + row * H + (((col >> 3) ^ (row & 7)) << 3) + (col & 7)) = hv;
    }
    __syncthreads();                                 // B1: xg ready

    // layer-1 half 0 (W1 fragments kk=0..3)
    {
        f16x8 wv[4][4];
        #pragma unroll
        for (int kk = 0; kk < 4; ++kk)
            #pragma unroll
            for (int nt = 0; nt < 4; ++nt)
                wv[kk][nt] = *(const f16x8*)(F1 + ((((wnt + nt) * 8 + kk) * 64 + l) << 3));
        #pragma unroll
        for (int kk = 0; kk < 4; ++kk) {
            int k = kk * 32 + (lg << 3);
            int slot = (((k >> 3) ^ (lr & 7)) << 3);
            f16x8 a0 = *(const f16x8*)(sA + (wRow + lr) * H + slot);
            f16x8 a1 = *(const f16x8*)(sA + (wRow + 16 + lr) * H + slot);
            #pragma unroll
            for (int nt = 0; nt < 4; ++nt) {
                acc[0][nt] = MFMA16(a0, wv[kk][nt], acc[0][nt]);
                acc[1][nt] = MFMA16(a1, wv[kk][nt], acc[1][nt]);
            }
        }
    }
    __syncthreads();                                 // B2: xg reads done

    // ---- phase 2: stage xs (fine rows) into the same buffer ----
    #pragma unroll
    for (int i = 0; i < 8; ++i) {
        int f = i * 256 + t;
        int row = f >> 5, col = (f & 31) * 4;
        float4 v = *(const float4*)(xsc + (long long)(R0 + row) * H + col);
        f16x4 hv; hv[0] = (f16)v.x; hv[1] = (f16)v.y; hv[2] = (f16)v.z; hv[3] = (f16)v.w;
        *(f16x4*)(sA + row * H + (((col >> 3) ^ (row & 7)) << 3) + (col & 7)) = hv;
    }
    __syncthreads();                                 // B3: xs ready

    // layer-1 half 1 (W1 fragments kk=4..7)
    {
        f16x8 wv[4][4];
        #pragma unroll
        for (int kk = 0; kk < 4; ++kk)
            #pragma unroll
            for (int nt = 0; nt < 4; ++nt)
                wv[kk][nt] = *(const f16x8*)(F1 + ((((wnt + nt) * 8 + kk + 4) * 64 + l) << 3));
        #pragma unroll
        for (int kk = 0; kk < 4; ++kk) {
            int k = kk * 32 + (lg << 3);
            int slot = (((k >> 3) ^ (lr & 7)) << 3);
            f16x8 a0 = *(const f16x8*)(sA + (wRow + lr) * H + slot);
            f16x8 a1 = *(const f16x8*)(sA + (wRow + 16 + lr) * H + slot);
            #pragma unroll
            for (int nt = 0; nt < 4; ++nt) {
                acc[0][nt] = MFMA16(a0, wv[kk][nt], acc[0][nt]);
                acc[1][nt] = MFMA16(a1, wv[kk][nt], acc[1][nt]);
            }
        }
    }
    __syncthreads();                                 // B4: xs reads done

    // h1 -> sA
    #pragma unroll
    for (int nt = 0; nt < 4; ++nt)
        #pragma unroll
        for (int mt = 0; mt < 2; ++mt)
            #pragma unroll
            for (int r = 0; r < 4; ++r) {
                int row = wRow + mt * 16 + lg * 4 + r;
                int col = (wnt + nt) * 16 + lr;
                sA[row * H + (((col >> 3) ^ (row & 7)) << 3) + (col & 7)] =
                    (f16)silu_f(acc[mt][nt][r]);
            }
    __syncthreads();                                 // B5: h1 ready

    // ---- layer 2 ----
    #pragma unroll
    for (int nt = 0; nt < 4; ++nt) {
        float bc = b2[(wnt + nt) * 16 + lr];
        #pragma unroll
        for (int mt = 0; mt < 2; ++mt)
            #pragma unroll
            for (int r = 0; r < 4; ++r)
                acc[mt][nt][r] = bc;
    }
    {
        f16x8 wv[4][4];
        #pragma unroll
        for (int kk = 0; kk < 4; ++kk)
            #pragma unroll
            for (int nt = 0; nt < 4; ++nt)
                wv[kk][nt] = *(const f16x8*)(F2 + ((((wnt + nt) * 4 + kk) * 64 + l) << 3));
        #pragma unroll
        for (int kk = 0; kk < 4; ++kk) {
            int k = kk * 32 + (lg << 3);
            int slot = (((k >> 3) ^ (lr & 7)) << 3);
            f16x8 a0 = *(const f16x8*)(sA + (wRow + lr) * H + slot);
            f16x8 a1 = *(const f16x8*)(sA + (wRow + 16 + lr) * H + slot);
            #pragma unroll
            for (int nt = 0; nt < 4; ++nt) {
                acc[0][nt] = MFMA16(a0, wv[kk][nt], acc[0][nt]);
                acc[1][nt] = MFMA16(a1, wv[kk][nt], acc[1][nt]);
            }
        }
    }
    __syncthreads();                                 // B6: h1 reads done

    // h2 -> sA
    #pragma unroll
    for (int nt = 0; nt < 4; ++nt)
        #pragma unroll
        for (int mt = 0; mt < 2; ++mt)
            #pragma unroll
            for (int r = 0; r < 4; ++r) {
                int row = wRow + mt * 16 + lg * 4 + r;
                int col = (wnt + nt) * 16 + lr;
                sA[row * H + (((col >> 3) ^ (row & 7)) << 3) + (col & 7)] =
                    (f16)silu_f(acc[mt][nt][r]);
            }
    __syncthreads();                                 // B7: h2 ready

    // ---- layer 3 ----
    #pragma unroll
    for (int nt = 0; nt < 4; ++nt) {
        float bc = b3[(wnt + nt) * 16 + lr];
        #pragma unroll
        for (int mt = 0; mt < 2; ++mt)
            #pragma unroll
            for (int r = 0; r < 4; ++r)
                acc[mt][nt][r] = bc;
    }
    {
        f16x8 wv[4][4];
        #pragma unroll
        for (int kk = 0; kk < 4; ++kk)
            #pragma unroll
            for (int nt = 0; nt < 4; ++nt)
                wv[kk][nt] = *(const f16x8*)(F3 + ((((wnt + nt) * 4 + kk) * 64 + l) << 3));
        #pragma unroll
        for (int kk = 0; kk < 4; ++kk) {
            int k = kk * 32 + (lg << 3);
            int slot = (((k >> 3) ^ (lr & 7)) << 3);
            f16x8 a0 = *(const f16x8*)(sA + (wRow + lr) * H + slot);
            f16x8 a1 = *(const f16x8*)(sA + (wRow + 16 + lr) * H + slot);
            #pragma unroll
            for (int nt = 0; nt < 4; ++nt) {
                acc[0][nt] = MFMA16(a0, wv[kk][nt], acc[0][nt]);
                acc[1][nt] = MFMA16(a1, wv[kk][nt], acc[1][nt]);
            }
        }
    }

    // ---- store out ----
    #pragma unroll
    for (int mt = 0; mt < 2; ++mt)
        #pragma unroll
        for (int nt = 0; nt < 4; ++nt)
            #pragma unroll
            for (int r = 0; r < 4; ++r) {
                long long row = (long long)R0 + wRow + mt * 16 + lg * 4 + r;
                int col = (wnt + nt) * 16 + lr;
                out[row * H + col] = acc[mt][nt][r];
            }
}

extern "C" void kernel_launch(void* const* d_in, const int* in_sizes, int n_in,
                              void* d_out, int out_size, void* d_ws, size_t ws_size,
                              hipStream_t stream)
{
    const float* x    = (const float*)d_in[0];
    const float* xsc  = (const float*)d_in[1];
    const int*   f2c  = (const int*)d_in[2];
    const float* dist = (const float*)d_in[3];
    const float* W1   = (const float*)d_in[4];
    const float* b1   = (const float*)d_in[5];
    const float* W2   = (const float*)d_in[6];
    const float* b2   = (const float*)d_in[7];
    const float* W3   = (const float*)d_in[8];
    const float* b3   = (const float*)d_in[9];
    f16* ws = (f16*)d_ws;

    prep_w<<<256, 256, 0, stream>>>(W1, W2, W3, ws);

    const int n_rows = 2 * NF;                    // 200000
    dim3 grid(n_rows / TM);                       // 3125
    fused_mlp_v11<<<grid, 256, 0, stream>>>(x, xsc, f2c, dist, W1, b1, b2, b3,
                                            ws, (float*)d_out);
}